// Round 10
// baseline (95.879 us; speedup 1.0000x reference)
//
#include <hip/hip_runtime.h>

// Problem constants (from reference)
constexpr int B_  = 16;
constexpr int NV_ = 10475;
constexpr int F_  = 20908;
constexpr int P_  = F_ * 8;              // 167264 pairs per batch (= 8 * F_)
constexpr float LINEAR_MAX_ = 1000.0f;
constexpr int PB_ = 82;                  // pair-blocks per batch (82*256 >= F_)

// Stage 1: 8 pairs per thread (stride F_, coalesced int2). Gathers run under
// the valid-pair exec mask (~25% density) so each scattered VMEM instruction
// generates ~16 lane-addresses instead of 64 (TA-throughput is the bottleneck).
// No atomics: each block writes one partial to a unique slot.
__global__ __launch_bounds__(256) void pen_partial_kernel(
    const float* __restrict__ v,        // (B, NV, 3) f32
    const int*   __restrict__ faces,    // (F, 3) i32
    const int2*  __restrict__ coll,     // (B, P) pairs
    float*       __restrict__ part)     // (B, PB_) partial sums
{
    const int b = blockIdx.y;
    const int p = blockIdx.x * blockDim.x + threadIdx.x;

    float psi2 = 0.0f;

    if (p < F_) {
        const float* __restrict__ vb = v + (size_t)b * (NV_ * 3);
        const int2*  __restrict__ cb = coll + (size_t)b * P_ + p;

        // Hoist the 8 coalesced pair loads (independent, all-lane).
        int2 prs[8];
        #pragma unroll
        for (int k = 0; k < 8; ++k) prs[k] = cb[k * F_];

        #pragma unroll
        for (int k = 0; k < 8; ++k) {
            const int2 pr = prs[k];
            if ((pr.x | pr.y) >= 0) {          // exec-masked gather region
                const int fR = pr.y * 3;       // receiver face
                const int fI = pr.x * 3;       // intruder face

                const int r0i = faces[fR + 0] * 3;
                const int r1i = faces[fR + 1] * 3;
                const int r2i = faces[fR + 2] * 3;
                const int a0i = faces[fI + 0] * 3;
                const int a1i = faces[fI + 1] * 3;
                const int a2i = faces[fI + 2] * 3;

                const float r0x = vb[r0i + 0], r0y = vb[r0i + 1], r0z = vb[r0i + 2];
                const float r1x = vb[r1i + 0], r1y = vb[r1i + 1], r1z = vb[r1i + 2];
                const float r2x = vb[r2i + 0], r2y = vb[r2i + 1], r2z = vb[r2i + 2];

                const float third = 1.0f / 3.0f;
                const float cx = (r0x + r1x + r2x) * third;
                const float cy = (r0y + r1y + r2y) * third;
                const float cz = (r0z + r1z + r2z) * third;

                const float e1x = r1x - r0x, e1y = r1y - r0y, e1z = r1z - r0z;
                const float e2x = r2x - r0x, e2y = r2y - r0y, e2z = r2z - r0z;
                float nx = e1y * e2z - e1z * e2y;
                float ny = e1z * e2x - e1x * e2z;
                float nz = e1x * e2y - e1y * e2x;
                const float inv = 1.0f / (sqrtf(nx * nx + ny * ny + nz * nz) + 1e-12f);
                nx *= inv; ny *= inv; nz *= inv;
                const float cdn = cx * nx + cy * ny + cz * nz;

                float s = 0.0f;
                {
                    float t = cdn - (vb[a0i + 0] * nx + vb[a0i + 1] * ny + vb[a0i + 2] * nz);
                    t = fminf(fmaxf(t, 0.0f), LINEAR_MAX_);
                    s = fmaf(t, t, s);
                }
                {
                    float t = cdn - (vb[a1i + 0] * nx + vb[a1i + 1] * ny + vb[a1i + 2] * nz);
                    t = fminf(fmaxf(t, 0.0f), LINEAR_MAX_);
                    s = fmaf(t, t, s);
                }
                {
                    float t = cdn - (vb[a2i + 0] * nx + vb[a2i + 1] * ny + vb[a2i + 2] * nz);
                    t = fminf(fmaxf(t, 0.0f), LINEAR_MAX_);
                    s = fmaf(t, t, s);
                }

                psi2 += s;
            }
        }
    }

    // wave64 shfl -> LDS across waves -> ONE plain store per block (no atomic)
    #pragma unroll
    for (int off = 32; off > 0; off >>= 1)
        psi2 += __shfl_down(psi2, off, 64);

    __shared__ float wsum[4];   // 256 threads = 4 waves
    const int lane = threadIdx.x & 63;
    const int wid  = threadIdx.x >> 6;
    if (lane == 0) wsum[wid] = psi2;
    __syncthreads();

    if (threadIdx.x == 0)
        part[b * PB_ + blockIdx.x] = wsum[0] + wsum[1] + wsum[2] + wsum[3];
}

// Stage 2: block b sums its 82 partials and writes out[b] (overwrites poison).
__global__ __launch_bounds__(128) void final_reduce_kernel(
    const float* __restrict__ part,     // (B, PB_)
    float*       __restrict__ out)      // (B,)
{
    const int b = blockIdx.x;
    const int t = threadIdx.x;

    float s = (t < PB_) ? part[b * PB_ + t] : 0.0f;

    #pragma unroll
    for (int off = 32; off > 0; off >>= 1)
        s += __shfl_down(s, off, 64);

    __shared__ float wsum[2];   // 128 threads = 2 waves
    if ((t & 63) == 0) wsum[t >> 6] = s;
    __syncthreads();

    if (t == 0) out[b] = wsum[0] + wsum[1];
}

extern "C" void kernel_launch(void* const* d_in, const int* in_sizes, int n_in,
                              void* d_out, int out_size, void* d_ws, size_t ws_size,
                              hipStream_t stream) {
    const float* v     = (const float*)d_in[0];
    const int*   faces = (const int*)d_in[1];
    const int2*  coll  = (const int2*)d_in[2];
    float* out  = (float*)d_out;
    float* part = (float*)d_ws;         // B_ * PB_ floats = 5.25 KB

    dim3 block(256);
    dim3 grid(PB_, B_);                 // 1312 blocks, 8 pairs/thread
    pen_partial_kernel<<<grid, block, 0, stream>>>(v, faces, coll, part);
    final_reduce_kernel<<<dim3(B_), dim3(128), 0, stream>>>(part, out);
}

// Round 11
// 92.916 us; speedup vs baseline: 1.0319x; 1.0319x over previous
//
#include <hip/hip_runtime.h>

// Problem constants (from reference)
constexpr int B_  = 16;
constexpr int NV_ = 10475;
constexpr int F_  = 20908;
constexpr int P_  = F_ * 8;              // 167264 pairs per batch
constexpr float LINEAR_MAX_ = 1000.0f;

constexpr int REC_PB_  = 82;             // record-blocks per batch (82*256 >= F_)
constexpr int PAIR_PB_ = 164;            // pair-blocks per batch (164*256*4 >= P_)
constexpr int QSTRIDE_ = PAIR_PB_ * 256; // 41984, per-thread pair stride

// d_ws layout:
//   tbl  : 64 B per (b,f) record, B_*F_*64 = 21.4 MB  (offset 0)
//   part : float[B_*PAIR_PB_]                          (offset 21.4 MB)
// Record (b,f): [0]{n.xyz, c·n} [1]{v0.xyz, v1.x} [2]{v1.yz, v2.xy} [3]{v2.z,-,-,-}

// XCD b-locality swizzle (consecutive bids round-robin the 8 XCDs):
// batch b's blocks + its 1.34 MB table slice stay on one XCD (2 batches/XCD).
// Performance heuristic only; correctness never depends on it.
__device__ __forceinline__ void swz(int bid, int& b, int& px) {
    const int xcd = bid & 7;
    const int j   = bid >> 3;
    b  = xcd + ((j & 1) << 3);
    px = j >> 1;
}

// Pass 1: build records. Stage 64B records in LDS, then write coalesced
// (4 sequential-line float4 stores per wave instead of 64-line scattered).
__global__ __launch_bounds__(256) void face_rec_kernel(
    const float* __restrict__ v,        // (B, NV, 3)
    const int*   __restrict__ faces,    // (F, 3)
    float4*      __restrict__ tbl)
{
    __shared__ float4 lds4[1024];       // 256 records * 4 float4 = 16 KB

    int b, px; swz(blockIdx.x, b, px);
    const int t  = threadIdx.x;
    const int f0 = px * 256;
    const int f  = f0 + t;
    const int fc = (f < F_) ? f : 0;    // clamp tail (avoid OOB faces read)

    const float* __restrict__ vb = v + (size_t)b * (NV_ * 3);
    const int i0 = faces[fc * 3 + 0] * 3;
    const int i1 = faces[fc * 3 + 1] * 3;
    const int i2 = faces[fc * 3 + 2] * 3;

    const float v0x = vb[i0 + 0], v0y = vb[i0 + 1], v0z = vb[i0 + 2];
    const float v1x = vb[i1 + 0], v1y = vb[i1 + 1], v1z = vb[i1 + 2];
    const float v2x = vb[i2 + 0], v2y = vb[i2 + 1], v2z = vb[i2 + 2];

    const float third = 1.0f / 3.0f;
    const float cx = (v0x + v1x + v2x) * third;
    const float cy = (v0y + v1y + v2y) * third;
    const float cz = (v0z + v1z + v2z) * third;

    const float e1x = v1x - v0x, e1y = v1y - v0y, e1z = v1z - v0z;
    const float e2x = v2x - v0x, e2y = v2y - v0y, e2z = v2z - v0z;
    float nx = e1y * e2z - e1z * e2y;
    float ny = e1z * e2x - e1x * e2z;
    float nz = e1x * e2y - e1y * e2x;
    const float inv = 1.0f / (sqrtf(nx * nx + ny * ny + nz * nz) + 1e-12f);
    nx *= inv; ny *= inv; nz *= inv;

    lds4[t * 4 + 0] = make_float4(nx, ny, nz, cx * nx + cy * ny + cz * nz);
    lds4[t * 4 + 1] = make_float4(v0x, v0y, v0z, v1x);
    lds4[t * 4 + 2] = make_float4(v1y, v1z, v2x, v2y);
    lds4[t * 4 + 3] = make_float4(v2z, 0.0f, 0.0f, 0.0f);
    __syncthreads();

    // Coalesced write-out. Guard so tail records (f >= F_) are NOT written
    // (they'd alias into batch b+1's record region).
    const int vrec  = F_ - f0;                        // valid records this block
    const int limit = ((vrec < 256) ? vrec : 256) * 4; // valid float4 count
    float4* dst = tbl + ((size_t)b * F_ + f0) * 4;
    #pragma unroll
    for (int j = 0; j < 4; ++j) {
        const int e = j * 256 + t;
        if (e < limit) dst[e] = lds4[e];
    }
}

// Pass 2: 4 pairs per thread (stride QSTRIDE_, coalesced int2). Per valid
// pair: 4 scattered float4 loads touching 2 cache lines. No atomics.
__global__ __launch_bounds__(256) void pen_pairs_kernel(
    const int2*   __restrict__ coll,    // (B, P)
    const float4* __restrict__ tbl,
    float*        __restrict__ part)    // (B, PAIR_PB_)
{
    int b, px; swz(blockIdx.x, b, px);
    const int p0 = px * 256 + threadIdx.x;

    const int2*   __restrict__ cb = coll + (size_t)b * P_;
    const float4* __restrict__ bt = tbl + (size_t)b * F_ * 4;

    float psi2 = 0.0f;

    #pragma unroll
    for (int k = 0; k < 4; ++k) {
        const int p = p0 + k * QSTRIDE_;
        if (p < P_) {
            const int2 pr = cb[p];
            const float m = ((pr.x | pr.y) >= 0) ? 1.0f : 0.0f;
            const int fR = (pr.y > 0) ? pr.y : 0;   // receiver
            const int fI = (pr.x > 0) ? pr.x : 0;   // intruder

            const float4 nd = bt[fR * 4 + 0];
            const float4 L0 = bt[fI * 4 + 1];
            const float4 L1 = bt[fI * 4 + 2];
            const float4 L2 = bt[fI * 4 + 3];

            float s = 0.0f;
            float t0 = nd.w - (L0.x * nd.x + L0.y * nd.y + L0.z * nd.z);
            t0 = fminf(fmaxf(t0, 0.0f), LINEAR_MAX_);
            s = fmaf(t0, t0, s);
            float t1 = nd.w - (L0.w * nd.x + L1.x * nd.y + L1.y * nd.z);
            t1 = fminf(fmaxf(t1, 0.0f), LINEAR_MAX_);
            s = fmaf(t1, t1, s);
            float t2 = nd.w - (L1.z * nd.x + L1.w * nd.y + L2.x * nd.z);
            t2 = fminf(fmaxf(t2, 0.0f), LINEAR_MAX_);
            s = fmaf(t2, t2, s);

            psi2 = fmaf(m, s, psi2);
        }
    }

    #pragma unroll
    for (int off = 32; off > 0; off >>= 1)
        psi2 += __shfl_down(psi2, off, 64);

    __shared__ float wsum[4];
    const int lane = threadIdx.x & 63;
    const int wid  = threadIdx.x >> 6;
    if (lane == 0) wsum[wid] = psi2;
    __syncthreads();

    if (threadIdx.x == 0)
        part[b * PAIR_PB_ + px] = wsum[0] + wsum[1] + wsum[2] + wsum[3];
}

// Pass 3: block b sums its 164 partials, writes out[b] (overwrites poison).
__global__ __launch_bounds__(256) void final_reduce_kernel(
    const float* __restrict__ part,     // (B, PAIR_PB_)
    float*       __restrict__ out)      // (B,)
{
    const int b = blockIdx.x;
    const int t = threadIdx.x;

    float s = (t < PAIR_PB_) ? part[b * PAIR_PB_ + t] : 0.0f;

    #pragma unroll
    for (int off = 32; off > 0; off >>= 1)
        s += __shfl_down(s, off, 64);

    __shared__ float wsum[4];
    if ((t & 63) == 0) wsum[t >> 6] = s;
    __syncthreads();

    if (t == 0) out[b] = wsum[0] + wsum[1] + wsum[2] + wsum[3];
}

extern "C" void kernel_launch(void* const* d_in, const int* in_sizes, int n_in,
                              void* d_out, int out_size, void* d_ws, size_t ws_size,
                              hipStream_t stream) {
    const float* v     = (const float*)d_in[0];
    const int*   faces = (const int*)d_in[1];
    const int2*  coll  = (const int2*)d_in[2];
    float* out  = (float*)d_out;

    float4* tbl  = (float4*)d_ws;
    float*  part = (float*)((char*)d_ws + (size_t)B_ * F_ * 64);

    dim3 block(256);
    face_rec_kernel   <<<dim3(16 * REC_PB_),  block, 0, stream>>>(v, faces, tbl);   // 1312
    pen_pairs_kernel  <<<dim3(16 * PAIR_PB_), block, 0, stream>>>(coll, tbl, part); // 2624
    final_reduce_kernel<<<dim3(B_),           block, 0, stream>>>(part, out);
}